// Round 1
// baseline (293.153 us; speedup 1.0000x reference)
//
#include <hip/hip_runtime.h>

#define NV   150000
#define CIN  32
#define COUT 64
#define KK   27
#define KC   13   // center tap (0,0,0)
#define EPSF 1e-5f

// ---------------------------------------------------------------------------
// K1: submanifold conv. 1 thread per output voxel, 64 fp32 accumulators.
// Center tap is always active (self). Sparse taps handled via per-lane
// bitmask loop so wave cost scales with max active taps per lane (~2), not 27.
// ---------------------------------------------------------------------------
__global__ __launch_bounds__(256) void k_conv(
    const float* __restrict__ feat,    // [NV, CIN]
    const float* __restrict__ weight,  // [27, CIN, COUT]
    const int*   __restrict__ nbr,     // [27, NV]
    float*       __restrict__ out)     // [NV, COUT]
{
    const int n = blockIdx.x * 256 + threadIdx.x;
    const bool valid = (n < NV);
    const int nn = valid ? n : (NV - 1);

    float4 acc[16];
#pragma unroll
    for (int j = 0; j < 16; ++j) acc[j] = make_float4(0.f, 0.f, 0.f, 0.f);

    // ---- center tap: k = 13, idx == self, weight address wave-uniform ----
    {
        const int idx = nbr[KC * NV + nn];
        const float4* fr = (const float4*)(feat + (long)idx * CIN);
        const float4* w4 = (const float4*)(weight + KC * CIN * COUT);
#pragma unroll 1
        for (int q = 0; q < CIN / 4; ++q) {
            float4 f = fr[q];
#pragma unroll
            for (int cc = 0; cc < 4; ++cc) {
                const float fv = (cc == 0) ? f.x : (cc == 1) ? f.y : (cc == 2) ? f.z : f.w;
                const int c = q * 4 + cc;
#pragma unroll
                for (int j = 0; j < 16; ++j) {
                    float4 w = w4[c * 16 + j];
                    acc[j].x += fv * w.x;
                    acc[j].y += fv * w.y;
                    acc[j].z += fv * w.z;
                    acc[j].w += fv * w.w;
                }
            }
        }
    }

    // ---- sparse taps: build active-k bitmask, then drain ----
    unsigned int kmask = 0u;
#pragma unroll 1
    for (int k = 0; k < KK; ++k) {
        if (k == KC) continue;
        const int idx = valid ? nbr[k * NV + nn] : -1;
        if (idx >= 0) kmask |= (1u << k);
    }

    while (kmask) {
        const int k = __ffs(kmask) - 1;
        kmask &= kmask - 1u;
        const int idx = nbr[k * NV + nn];
        const float4* fr = (const float4*)(feat + (long)idx * CIN);
        const float4* w4 = (const float4*)(weight + k * CIN * COUT);
#pragma unroll 1
        for (int q = 0; q < CIN / 4; ++q) {
            float4 f = fr[q];
#pragma unroll
            for (int cc = 0; cc < 4; ++cc) {
                const float fv = (cc == 0) ? f.x : (cc == 1) ? f.y : (cc == 2) ? f.z : f.w;
                const int c = q * 4 + cc;
#pragma unroll
                for (int j = 0; j < 16; ++j) {
                    float4 w = w4[c * 16 + j];
                    acc[j].x += fv * w.x;
                    acc[j].y += fv * w.y;
                    acc[j].z += fv * w.z;
                    acc[j].w += fv * w.w;
                }
            }
        }
    }

    if (valid) {
        float4* o = (float4*)(out + (long)n * COUT);
#pragma unroll
        for (int j = 0; j < 16; ++j) o[j] = acc[j];
    }
}

// ---------------------------------------------------------------------------
// K2: per-block partial column sums & sums-of-squares over out [NV, 64].
// stride (gridDim*256) is a multiple of 16 -> each thread owns a fixed
// 4-channel group (tid % 16), fully coalesced float4 reads.
// ---------------------------------------------------------------------------
__global__ __launch_bounds__(256) void k_stats_partial(
    const float* __restrict__ out,       // [NV, COUT]
    float*       __restrict__ partials)  // [gridDim.x, 128] (64 sum + 64 sq)
{
    const long total4 = (long)NV * COUT / 4;  // 2,400,000
    const int  tid    = blockIdx.x * 256 + threadIdx.x;
    const int  stride = gridDim.x * 256;

    float sx = 0.f, sy = 0.f, sz = 0.f, sw = 0.f;
    float qx = 0.f, qy = 0.f, qz = 0.f, qw = 0.f;
    const float4* o4 = (const float4*)out;
    for (long i = tid; i < total4; i += stride) {
        float4 v = o4[i];
        sx += v.x; sy += v.y; sz += v.z; sw += v.w;
        qx += v.x * v.x; qy += v.y * v.y; qz += v.z * v.z; qw += v.w * v.w;
    }

    __shared__ float4 ls[256];
    __shared__ float4 lq[256];
    ls[threadIdx.x] = make_float4(sx, sy, sz, sw);
    lq[threadIdx.x] = make_float4(qx, qy, qz, qw);
    __syncthreads();

    if (threadIdx.x < 16) {
        float4 S = make_float4(0.f, 0.f, 0.f, 0.f);
        float4 Q = make_float4(0.f, 0.f, 0.f, 0.f);
        for (int t = threadIdx.x; t < 256; t += 16) {
            float4 a = ls[t];
            float4 b = lq[t];
            S.x += a.x; S.y += a.y; S.z += a.z; S.w += a.w;
            Q.x += b.x; Q.y += b.y; Q.z += b.z; Q.w += b.w;
        }
        float* p = partials + (long)blockIdx.x * 128;
        const int c0 = threadIdx.x * 4;
        p[c0 + 0] = S.x; p[c0 + 1] = S.y; p[c0 + 2] = S.z; p[c0 + 3] = S.w;
        p[64 + c0 + 0] = Q.x; p[64 + c0 + 1] = Q.y; p[64 + c0 + 2] = Q.z; p[64 + c0 + 3] = Q.w;
    }
}

// ---------------------------------------------------------------------------
// K2b: reduce partials, produce scale = gamma*rstd, shift = beta - mean*scale.
// ---------------------------------------------------------------------------
__global__ __launch_bounds__(128) void k_stats_final(
    const float* __restrict__ partials,
    const float* __restrict__ gamma,
    const float* __restrict__ beta,
    float*       __restrict__ stats,   // [128]: 64 scale, 64 shift
    int nblocks)
{
    const int t = threadIdx.x;  // 128 threads
    float s = 0.f;
    for (int b = 0; b < nblocks; ++b) s += partials[(long)b * 128 + t];
    __shared__ float ls[128];
    ls[t] = s;
    __syncthreads();
    if (t < 64) {
        const float inv_n = 1.f / (float)NV;
        const float mean = ls[t] * inv_n;
        float var = ls[64 + t] * inv_n - mean * mean;
        var = fmaxf(var, 0.f);
        const float rstd = rsqrtf(var + EPSF);
        const float scale = gamma[t] * rstd;
        const float shift = beta[t] - mean * scale;
        stats[t] = scale;
        stats[64 + t] = shift;
    }
}

// ---------------------------------------------------------------------------
// K3: in-place affine + ReLU. Exactly 2,400,000 float4 chunks = 9375 x 256.
// chunk % 16 == threadIdx.x % 16 gives the channel group.
// ---------------------------------------------------------------------------
__global__ __launch_bounds__(256) void k_norm(
    float* __restrict__ out,
    const float* __restrict__ stats)
{
    __shared__ float4 sc[16];
    __shared__ float4 sh[16];
    if (threadIdx.x < 16) {
        sc[threadIdx.x] = ((const float4*)stats)[threadIdx.x];
        sh[threadIdx.x] = ((const float4*)(stats + 64))[threadIdx.x];
    }
    __syncthreads();

    const long i = (long)blockIdx.x * 256 + threadIdx.x;  // chunk id
    const int  g = threadIdx.x & 15;
    float4 v = ((const float4*)out)[i];
    const float4 S = sc[g];
    const float4 H = sh[g];
    v.x = fmaxf(v.x * S.x + H.x, 0.f);
    v.y = fmaxf(v.y * S.y + H.y, 0.f);
    v.z = fmaxf(v.z * S.z + H.z, 0.f);
    v.w = fmaxf(v.w * S.w + H.w, 0.f);
    ((float4*)out)[i] = v;
}

// ---------------------------------------------------------------------------
extern "C" void kernel_launch(void* const* d_in, const int* in_sizes, int n_in,
                              void* d_out, int out_size, void* d_ws, size_t ws_size,
                              hipStream_t stream) {
    const float* feat   = (const float*)d_in[0];
    const float* weight = (const float*)d_in[1];
    const float* gamma  = (const float*)d_in[2];
    const float* beta   = (const float*)d_in[3];
    const int*   nbr    = (const int*)d_in[4];
    float* out = (float*)d_out;

    float* partials = (float*)d_ws;           // 128 blocks * 128 floats = 64 KB
    float* stats    = partials + 128 * 128;   // 128 floats

    const int STAT_BLOCKS = 128;

    k_conv<<<(NV + 255) / 256, 256, 0, stream>>>(feat, weight, nbr, out);
    k_stats_partial<<<STAT_BLOCKS, 256, 0, stream>>>(out, partials);
    k_stats_final<<<1, 128, 0, stream>>>(partials, gamma, beta, stats, STAT_BLOCKS);
    k_norm<<<(NV * COUT / 4) / 256, 256, 0, stream>>>(out, stats);
}